// Round 22
// baseline (163.124 us; speedup 1.0000x reference)
//
#include <hip/hip_runtime.h>
#include <math.h>

#define N_ 128
#define I_ 256
#define O_ 256
#define P_ 16
#define OT 4      // o's per block (site kernel)
#define IT 8      // i's per block (fallback kernel)
#define ITB 8     // i's per block (site kernel; R22: atomics gone -> TLP wins)
#define NSB 2048  // site blocks
#define ICH 4     // fallback kernel chunking
#define SQRT_2PI 2.5066282746310002f
#define INV_SQRT_2PI 0.3989422804014327f
#define NHALF_LOG2E 0.72134752044448170f   // 0.5 * log2(e)

// ---- Workspace layout ----
// floats [0, 4096*GF)           : packed records v3 (M f16, w/z/sc f32)
// floats [PM_OFF ...)           : pmean[block][ol][n]  (2048*4*128)
// floats [PV_OFF ...)           : pvar  same layout
// Ladder: f16-M -10; ITB=16 -27 (atomic halving); f16 passB -16; su2-f16
// -4; partial-stores+reduce -23 (atomics DELETED, WRITE 32768->4096).
// R22: with atomics gone, R16/R18's "big blocks win" rule inverts — ITB=8
// gives 25KB LDS -> 6 blocks/CU (vs 3), filling the 30% stall at VALU 70%.
#define GF 2048                    // floats per 16-pair group
#define PM_OFF ((size_t)4096 * GF)             // 8,388,608 floats
#define PV_OFF (PM_OFF + (size_t)NSB * 4 * 128)
#define NEED_BYTES ((PV_OFF + (size_t)NSB * 4 * 128) * 4)   // 41.9 MB

#define TRI(r, c) ((r) * ((r) + 1) / 2 + (c))

typedef float f2 __attribute__((ext_vector_type(2)));
typedef _Float16 h2 __attribute__((ext_vector_type(2)));

__device__ __forceinline__ float fast_tanh(float x) {
    const float e2 = __expf(2.0f * x);
    return 1.0f - 2.0f / (e2 + 1.0f);
}

// f32x2 -> packed f16x2 (round-nearest via scalar casts)
__device__ __forceinline__ uint32_t pkh(float a, float b) {
    h2 h;
    h.x = (_Float16)a;
    h.y = (_Float16)b;
    return __builtin_bit_cast(uint32_t, h);
}

// ============================ Kernel 1: pairs ==============================
// Serial per-thread Cholesky + in-place inversion + w (measured best of 6
// structural variants, ~27us = near its serial-latency floor at the
// structural 1 wave/SIMD); store packs M to f16 RN.
__global__ __launch_bounds__(64, 1) void gp_pairs(
    const float* __restrict__ z_param, const float* __restrict__ h,
    const float* __restrict__ l_param, const float* __restrict__ s_param,
    const float* __restrict__ jitter_param, float* __restrict__ ws)
{
    const int q = blockIdx.x * 64 + threadIdx.x;   // pair index = i*256 + o
    const int io = q;

    const float l   = __expf(l_param[io]) + 0.2f;
    const float s   = __expf(s_param[io]) + 0.1f;
    const float jit = __expf(jitter_param[io]) + 0.01f;
    const float l2 = l * l;
    const float ninv2l2 = -0.5f / l2;
    const float cQ = INV_SQRT_2PI / l;
    const float noise = jit * jit / (s * s * l * SQRT_2PI);
    const float s2l = s * s * l;

    float zv[P_], hv[P_];
    {
        const float4* zp = (const float4*)(z_param + (size_t)io * P_);
        const float4* hp = (const float4*)(h + (size_t)io * P_);
        #pragma unroll
        for (int c = 0; c < 4; ++c) {
            const float4 z4 = zp[c], h4 = hp[c];
            zv[4*c+0] = z4.x; zv[4*c+1] = z4.y; zv[4*c+2] = z4.z; zv[4*c+3] = z4.w;
            hv[4*c+0] = h4.x; hv[4*c+1] = h4.y; hv[4*c+2] = h4.z; hv[4*c+3] = h4.w;
        }
    }
    #pragma unroll
    for (int p = 0; p < P_; ++p) zv[p] = fast_tanh(zv[p]);

    float A[136];
    #pragma unroll
    for (int r = 0; r < P_; ++r) {
        #pragma unroll
        for (int c = 0; c <= r; ++c) {
            const float d = zv[r] - zv[c];
            A[TRI(r, c)] = cQ * __expf(d * d * ninv2l2) + ((r == c) ? noise : 0.f);
        }
    }

    float dinv[P_];
    #pragma unroll
    for (int k = 0; k < P_; ++k) {
        const float Lkk = sqrtf(A[TRI(k, k)]);
        const float ik = 1.0f / Lkk;
        dinv[k] = ik;
        A[TRI(k, k)] = Lkk;
        #pragma unroll
        for (int r = k + 1; r < P_; ++r) A[TRI(r, k)] *= ik;
        #pragma unroll
        for (int c = k + 1; c < P_; ++c) {
            const float Lck = A[TRI(c, k)];
            #pragma unroll
            for (int r = c; r < P_; ++r) A[TRI(r, c)] -= A[TRI(r, k)] * Lck;
        }
    }

    #pragma unroll
    for (int j = 0; j < P_; ++j) {
        #pragma unroll
        for (int r = j + 1; r < P_; ++r) {
            float acc = A[TRI(r, j)] * dinv[j];
            #pragma unroll
            for (int k = j + 1; k < r; ++k) acc += A[TRI(r, k)] * A[TRI(k, j)];
            A[TRI(r, j)] = -dinv[r] * acc;
        }
        A[TRI(j, j)] = dinv[j];
    }

    float tv[P_], wv[P_];
    #pragma unroll
    for (int r = 0; r < P_; ++r) {
        float acc = 0.f;
        #pragma unroll
        for (int c = 0; c <= r; ++c) acc += A[TRI(r, c)] * hv[c];
        tv[r] = acc;
    }
    #pragma unroll
    for (int c = 0; c < P_; ++c) {
        float acc = 0.f;
        #pragma unroll
        for (int r = c; r < P_; ++r) acc += A[TRI(r, c)] * tv[r];
        wv[c] = acc;
    }

    // ---- store packed record v3 ----
    float4* rb = (float4*)ws + (size_t)(q >> 4) * (GF / 4) + (size_t)(q & 15) * 4;
    {
        float4 buf[4];
        uint32_t us[4];
        int ucnt = 0, f4 = 0;
        #pragma unroll
        for (int m = 0; m < P_; ++m) {
            #pragma unroll
            for (int c = (m >> 2); c < 4; ++c) {
                float vv[4];
                #pragma unroll
                for (int rr = 0; rr < 4; ++rr) {
                    const int r = 4 * c + rr;
                    vv[rr] = (r < m) ? 0.f : A[TRI(r, m)];
                }
                us[ucnt]     = pkh(vv[0], vv[1]);
                us[ucnt + 1] = pkh(vv[2], vv[3]);
                ucnt += 2;
                if (ucnt == 4) {
                    buf[f4 & 3] = make_float4(
                        __uint_as_float(us[0]), __uint_as_float(us[1]),
                        __uint_as_float(us[2]), __uint_as_float(us[3]));
                    ucnt = 0;
                    if ((f4 & 3) == 3) {
                        float4* up = rb + (size_t)(f4 >> 2) * 64;
                        up[0] = buf[0]; up[1] = buf[1]; up[2] = buf[2]; up[3] = buf[3];
                    }
                    ++f4;
                }
            }
        }
    }
    {
        float4* zp = rb + 5 * 64;
        zp[0] = make_float4(zv[ 0], zv[ 1], zv[ 2], zv[ 3]);
        zp[1] = make_float4(zv[ 4], zv[ 5], zv[ 6], zv[ 7]);
        zp[2] = make_float4(zv[ 8], zv[ 9], zv[10], zv[11]);
        zp[3] = make_float4(zv[12], zv[13], zv[14], zv[15]);
        float4* wp = rb + 6 * 64;
        wp[0] = make_float4(wv[ 0], wv[ 1], wv[ 2], wv[ 3]);
        wp[1] = make_float4(wv[ 4], wv[ 5], wv[ 6], wv[ 7]);
        wp[2] = make_float4(wv[ 8], wv[ 9], wv[10], wv[11]);
        wp[3] = make_float4(wv[12], wv[13], wv[14], wv[15]);
        float4* sp = rb + 7 * 64;
        sp[0] = make_float4(l2, s2l, 0.f, 0.f);
    }
}

// ============================ Kernel 2: sites ==============================
// R22: ITB=8, grid 2048, LDS ~25KB -> 6 blocks/CU (vs R21's 3). Atomic-free
// partial stores; f16 pass B + su2; exp2-folded pass A.
__global__ __launch_bounds__(256, 6) void gp_sites(
    const float* __restrict__ x_mean, const float* __restrict__ x_var,
    const float* __restrict__ ws, float* __restrict__ wsw)
{
    __shared__ float xm_s[N_][ITB + 1];
    __shared__ float xv_s[N_][ITB + 1];
    __shared__ __align__(16) float4 pbv[32 * 32];   // 32 records x 512B

    const int t = threadIdx.x;
    const int b = blockIdx.x;
    const int ot = b & 63;
    const int ir = b >> 6;          // 0..31
    const int i0 = ir * ITB;

    // stage x slice (8 i's x 128 n)
    {
        const int n = t >> 1, qq = t & 1;
        const float4 xm4 = *(const float4*)(x_mean + n * I_ + i0 + qq * 4);
        const float4 xv4 = *(const float4*)(x_var  + n * I_ + i0 + qq * 4);
        xm_s[n][qq*4+0] = xm4.x; xm_s[n][qq*4+1] = xm4.y;
        xm_s[n][qq*4+2] = xm4.z; xm_s[n][qq*4+3] = xm4.w;
        xv_s[n][qq*4+0] = xv4.x; xv_s[n][qq*4+1] = xv4.y;
        xv_s[n][qq*4+2] = xv4.z; xv_s[n][qq*4+3] = xv4.w;
    }

    // stage all 32 records (8 i x 4 o), coalesced: exactly 1024 float4s
    {
        const int g_hi = ot >> 2;
        const int s0x4 = (ot & 3) * 16;         // s0*4 in float4 units
        const float4* wsv = (const float4*)ws;
        #pragma unroll
        for (int k = 0; k < 4; ++k) {
            const int idx = t + k * 256;
            const int run = idx >> 4;           // 0..63 = i*8 + j
            const int f4i = idx & 15;           // ol*4 + c
            const int i = run >> 3;
            const int j = run & 7;
            const int gi = (i0 + i) * 16 + g_hi;
            const float4 v = wsv[(size_t)gi * (GF / 4) + j * 64 + s0x4 + f4i];
            pbv[(i * 4 + (f4i >> 2)) * 32 + j * 4 + (f4i & 3)] = v;
        }
    }
    __syncthreads();

    f2 am2 = {0.f, 0.f};
    f2 av2 = {ITB * 0.1f, ITB * 0.1f};   // GLOBAL_JITTER per i

    const int ol = t >> 6;   // o_local (0..3), one per wave
    const int ln = t & 63;   // sites n = ln and ln+64

    // chunk lk -> (column m, row-quad c), producer's order (R5-verified)
    constexpr int MKt[40] = {0,0,0,0, 1,1,1,1, 2,2,2,2, 3,3,3,3,
                             4,4,4, 5,5,5, 6,6,6, 7,7,7,
                             8,8, 9,9, 10,10, 11,11, 12, 13, 14, 15};
    constexpr int CKt[40] = {0,1,2,3, 0,1,2,3, 0,1,2,3, 0,1,2,3,
                             1,2,3, 1,2,3, 1,2,3, 1,2,3,
                             2,3, 2,3, 2,3, 2,3, 3, 3, 3, 3};

    for (int ii = 0; ii < ITB; ++ii) {
        const float4* rp = &pbv[(ii * 4 + ol) * 32];

        const float4 scv = rp[28];
        const float l2  = scv.x;
        const float s2l = scv.y;
        const float t4v = SQRT_2PI * s2l;

        float zr[P_], wr[P_];
        #pragma unroll
        for (int c = 0; c < 4; ++c) {
            const float4 z4 = rp[20 + c], w4 = rp[24 + c];
            zr[4*c+0] = z4.x; zr[4*c+1] = z4.y; zr[4*c+2] = z4.z; zr[4*c+3] = z4.w;
            wr[4*c+0] = w4.x; wr[4*c+1] = w4.y; wr[4*c+2] = w4.z; wr[4*c+3] = w4.w;
        }

        f2 xm2, xv2;
        xm2.x = xm_s[ln][ii];       xm2.y = xm_s[ln + 64][ii];
        xv2.x = xv_s[ln][ii];       xv2.y = xv_s[ln + 64][ii];
        f2 v2 = xv2 + l2;
        f2 cc2, nh2;
        cc2.x = rsqrtf(v2.x) * INV_SQRT_2PI;
        cc2.y = rsqrtf(v2.y) * INV_SQRT_2PI;
        nh2.x = -NHALF_LOG2E / v2.x;   // -0.5*log2e/v: em = exp2(d^2*nh2)
        nh2.y = -NHALF_LOG2E / v2.y;

        // ---- pass A: all 16 em2 (f32), dm2 (f32, parity-split) ----
        f2 em2[P_];
        h2 em2h[P_];
        f2 dm2a = {0.f, 0.f}, dm2b = {0.f, 0.f};
        #pragma unroll
        for (int m = 0; m < P_; ++m) {
            f2 d2 = xm2 - zr[m];
            f2 tt = d2 * d2 * nh2;
            em2[m].x = __builtin_amdgcn_exp2f(tt.x);
            em2[m].y = __builtin_amdgcn_exp2f(tt.y);
            em2h[m].x = (_Float16)em2[m].x;
            em2h[m].y = (_Float16)em2[m].y;
            if (m & 1) dm2b += em2[m] * wr[m];
            else       dm2a += em2[m] * wr[m];
        }
        const f2 dm2 = dm2a + dm2b;

        // ---- pass B: 20 float4 reads = 40 f16 chunks, native f16 pk-fma ----
        h2 u2h[P_];
        #pragma unroll
        for (int tt = 0; tt < 20; ++tt) {
            const float4 F = rp[tt];
            const h2 pa = __builtin_bit_cast(h2, F.x);
            const h2 pb = __builtin_bit_cast(h2, F.y);
            const h2 pc = __builtin_bit_cast(h2, F.z);
            const h2 pd = __builtin_bit_cast(h2, F.w);
            {   // chunk 2*tt : values pa.x pa.y pb.x pb.y
                const int lk = 2 * tt;
                const int m = MKt[lk], c = CKt[lk];
                if (lk < 4) {
                    u2h[4*c+0] = pa.x * em2h[m];
                    u2h[4*c+1] = pa.y * em2h[m];
                    u2h[4*c+2] = pb.x * em2h[m];
                    u2h[4*c+3] = pb.y * em2h[m];
                } else {
                    u2h[4*c+0] += pa.x * em2h[m];
                    u2h[4*c+1] += pa.y * em2h[m];
                    u2h[4*c+2] += pb.x * em2h[m];
                    u2h[4*c+3] += pb.y * em2h[m];
                }
            }
            {   // chunk 2*tt+1 : values pc.x pc.y pd.x pd.y
                const int lk = 2 * tt + 1;
                const int m = MKt[lk], c = CKt[lk];
                if (lk < 4) {
                    u2h[4*c+0] = pc.x * em2h[m];
                    u2h[4*c+1] = pc.y * em2h[m];
                    u2h[4*c+2] = pd.x * em2h[m];
                    u2h[4*c+3] = pd.y * em2h[m];
                } else {
                    u2h[4*c+0] += pc.x * em2h[m];
                    u2h[4*c+1] += pc.y * em2h[m];
                    u2h[4*c+2] += pd.x * em2h[m];
                    u2h[4*c+3] += pd.y * em2h[m];
                }
            }
        }

        // ---- su2 accumulated packed-f16 (parity-split), one up-convert ----
        h2 su2ha = {(_Float16)0.f, (_Float16)0.f};
        h2 su2hb = {(_Float16)0.f, (_Float16)0.f};
        #pragma unroll
        for (int r = 0; r < P_; r += 2) {
            su2ha += u2h[r]   * u2h[r];
            su2hb += u2h[r+1] * u2h[r+1];
        }
        const h2 su2h = su2ha + su2hb;
        f2 su2;
        su2.x = (float)su2h.x;
        su2.y = (float)su2h.y;

        am2 += cc2 * dm2;
        f2 t32;
        t32.x = s2l * rsqrtf(l2 + 2.f * xv2.x);
        t32.y = s2l * rsqrtf(l2 + 2.f * xv2.y);
        av2 += t32 - t4v * (cc2 * cc2) * su2;
    }

    // ---- coalesced partial stores (no atomics) ----
    float* pm = wsw + PM_OFF + ((size_t)b * 4 + ol) * 128;
    float* pv = wsw + PV_OFF + ((size_t)b * 4 + ol) * 128;
    pm[ln]      = am2.x;
    pm[ln + 64] = am2.y;
    pv[ln]      = av2.x;
    pv[ln + 64] = av2.y;
}

// ============================ Kernel 3: reduce =============================
// out[n][o] = sum_ir pmean[(ir*64+ot)*4+ol][n]; same for var. One block per
// o (256 blocks x 128 threads = n); partial loads coalesced (lanes = n).
__global__ __launch_bounds__(128, 8) void gp_reduce(
    const float* __restrict__ ws, float* __restrict__ out)
{
    const int o = blockIdx.x;
    const int n = threadIdx.x;
    const int ot = o >> 2;
    const int ol = o & 3;

    const float* pm = ws + PM_OFF;
    const float* pv = ws + PV_OFF;

    float sm = 0.f, sv = 0.f;
    #pragma unroll
    for (int ir = 0; ir < 32; ++ir) {
        const size_t base = (((size_t)ir * 64 + ot) * 4 + ol) * 128 + n;
        sm += pm[base];
        sv += pv[base];
    }
    out[n * O_ + o] = sm;
    out[N_ * O_ + n * O_ + o] = sv;
}

// ===================== Fallback: R5 monolithic kernel ======================
#define LSTR 20
__global__ __launch_bounds__(256, 2) void gp_fused(
    const float* __restrict__ x_mean, const float* __restrict__ x_var,
    const float* __restrict__ z_param, const float* __restrict__ h,
    const float* __restrict__ l_param, const float* __restrict__ s_param,
    const float* __restrict__ jitter_param, float* __restrict__ out)
{
    __shared__ float xm_s[N_][IT + 1];
    __shared__ float xv_s[N_][IT + 1];
    __shared__ __align__(16) float LinvT[ICH][OT][P_][LSTR];
    __shared__ __align__(16) float zS[ICH][OT][P_];
    __shared__ __align__(16) float wS[ICH][OT][P_];
    __shared__ float scS[ICH][OT][2];

    const int t = threadIdx.x;
    const int b = blockIdx.x;
    const int ot = b & 63;
    const int ir = b >> 6;
    const int o_base = ot * OT;
    const int i0 = ir * IT;

    {
        const int n = t >> 1, q = t & 1;
        const float4 xm4 = *(const float4*)(x_mean + n * I_ + i0 + q * 4);
        const float4 xv4 = *(const float4*)(x_var  + n * I_ + i0 + q * 4);
        xm_s[n][q*4+0] = xm4.x; xm_s[n][q*4+1] = xm4.y;
        xm_s[n][q*4+2] = xm4.z; xm_s[n][q*4+3] = xm4.w;
        xv_s[n][q*4+0] = xv4.x; xv_s[n][q*4+1] = xv4.y;
        xv_s[n][q*4+2] = xv4.z; xv_s[n][q*4+3] = xv4.w;
    }
    __syncthreads();

    f2 am2 = {0.f, 0.f};
    f2 av2 = {IT * 0.1f, IT * 0.1f};

    const int ol = t >> 6;
    const int ln = t & 63;
    const int g2 = t >> 4;
    const int il = g2 >> 2;
    const int g  = g2 & 3;
    const int p  = t & 15;

    for (int ii4 = 0; ii4 < IT / ICH; ++ii4) {
        {
            const int i  = i0 + ii4 * ICH + il;
            const int o  = o_base + g;
            const int io = i * O_ + o;
            const float l   = expf(l_param[io]) + 0.2f;
            const float s   = expf(s_param[io]) + 0.1f;
            const float jit = expf(jitter_param[io]) + 0.01f;
            const float l2 = l * l;
            const float inv2l2 = 0.5f / l2;
            const float cQ = INV_SQRT_2PI / l;
            const float noise = jit * jit / (s * s * l * SQRT_2PI);
            const float zp = tanhf(z_param[io * P_ + p]);

            float a[P_];
            #pragma unroll
            for (int c = 0; c < P_; ++c) {
                const float zc = __shfl(zp, c, P_);
                const float d = zp - zc;
                a[c] = cQ * __expf(-d * d * inv2l2) + ((c == p) ? noise : 0.0f);
            }
            #pragma unroll
            for (int k = 0; k < P_; ++k) {
                const float akk = __shfl(a[k], k, P_);
                const float lkk = sqrtf(akk);
                const float inv_lkk = 1.0f / lkk;
                if (p == k)      a[k] = lkk;
                else if (p > k)  a[k] *= inv_lkk;
                const float lrk = a[k];
                #pragma unroll
                for (int c = k + 1; c < P_; ++c) {
                    const float lck = __shfl(a[k], c, P_);
                    if (p >= c) a[c] -= lrk * lck;
                }
            }
            float x[P_];
            #pragma unroll
            for (int r = 0; r < P_; ++r) {
                const float lrr = __shfl(a[r], r, P_);
                float acc = (r == p) ? 1.0f : 0.0f;
                #pragma unroll
                for (int m = 0; m < r; ++m) {
                    const float lrm = __shfl(a[m], r, P_);
                    acc -= lrm * x[m];
                }
                x[r] = acc / lrr;
            }
            const float hc = h[io * P_ + p];
            float y[P_];
            #pragma unroll
            for (int r = 0; r < P_; ++r) y[r] = x[r] * hc;
            #pragma unroll
            for (int off = 8; off >= 1; off >>= 1) {
                #pragma unroll
                for (int r = 0; r < P_; ++r) y[r] += __shfl_xor(y[r], off, P_);
            }
            float wc = 0.f;
            #pragma unroll
            for (int r = 0; r < P_; ++r) wc += x[r] * y[r];

            float4* dst = (float4*)&LinvT[il][g][p][0];
            dst[0] = make_float4(x[ 0], x[ 1], x[ 2], x[ 3]);
            dst[1] = make_float4(x[ 4], x[ 5], x[ 6], x[ 7]);
            dst[2] = make_float4(x[ 8], x[ 9], x[10], x[11]);
            dst[3] = make_float4(x[12], x[13], x[14], x[15]);
            zS[il][g][p] = zp;
            wS[il][g][p] = wc;
            if (p == 0) { scS[il][g][0] = l2; scS[il][g][1] = s * s * l; }
        }
        __syncthreads();

        #pragma unroll
        for (int il2 = 0; il2 < ICH; ++il2) {
            const int iiA = ii4 * ICH + il2;
            const float l2  = scS[il2][ol][0];
            const float s2l = scS[il2][ol][1];
            const float t4v = SQRT_2PI * s2l;
            float zr[P_], wr[P_];
            {
                const float4* zp4 = (const float4*)&zS[il2][ol][0];
                const float4* wp4 = (const float4*)&wS[il2][ol][0];
                #pragma unroll
                for (int c = 0; c < 4; ++c) {
                    const float4 z4 = zp4[c], w4 = wp4[c];
                    zr[4*c+0] = z4.x; zr[4*c+1] = z4.y; zr[4*c+2] = z4.z; zr[4*c+3] = z4.w;
                    wr[4*c+0] = w4.x; wr[4*c+1] = w4.y; wr[4*c+2] = w4.z; wr[4*c+3] = w4.w;
                }
            }
            f2 xm2, xv2;
            xm2.x = xm_s[ln][iiA];       xm2.y = xm_s[ln + 64][iiA];
            xv2.x = xv_s[ln][iiA];       xv2.y = xv_s[ln + 64][iiA];
            f2 v2 = xv2 + l2;
            f2 cc2, nh2;
            cc2.x = rsqrtf(v2.x) * INV_SQRT_2PI;
            cc2.y = rsqrtf(v2.y) * INV_SQRT_2PI;
            nh2.x = -0.5f / v2.x;
            nh2.y = -0.5f / v2.y;
            f2 dm2 = {0.f, 0.f};
            f2 u2[P_];
            #pragma unroll
            for (int m = 0; m < P_; ++m) {
                f2 d2 = xm2 - zr[m];
                f2 tt = d2 * d2 * nh2;
                f2 em2;
                em2.x = __expf(tt.x);
                em2.y = __expf(tt.y);
                dm2 += em2 * wr[m];
                const int c0 = m >> 2;
                #pragma unroll
                for (int c = 0; c < 4; ++c) {
                    if (c < c0) continue;
                    const float4 L4 = *(const float4*)&LinvT[il2][ol][m][4*c];
                    if (m == 0) {
                        u2[4*c+0] = L4.x * em2;
                        u2[4*c+1] = L4.y * em2;
                        u2[4*c+2] = L4.z * em2;
                        u2[4*c+3] = L4.w * em2;
                    } else {
                        u2[4*c+0] += L4.x * em2;
                        u2[4*c+1] += L4.y * em2;
                        u2[4*c+2] += L4.z * em2;
                        u2[4*c+3] += L4.w * em2;
                    }
                }
            }
            f2 su2 = {0.f, 0.f};
            #pragma unroll
            for (int r = 0; r < P_; ++r) su2 += u2[r] * u2[r];
            am2 += cc2 * dm2;
            f2 t32;
            t32.x = s2l * rsqrtf(l2 + 2.f * xv2.x);
            t32.y = s2l * rsqrtf(l2 + 2.f * xv2.y);
            av2 += t32 - t4v * (cc2 * cc2) * su2;
        }
        __syncthreads();
    }

    const int o = o_base + ol;
    atomicAdd(out + ln * O_ + o,                  am2.x);
    atomicAdd(out + (ln + 64) * O_ + o,           am2.y);
    atomicAdd(out + N_ * O_ + ln * O_ + o,        av2.x);
    atomicAdd(out + N_ * O_ + (ln + 64) * O_ + o, av2.y);
}

extern "C" void kernel_launch(void* const* d_in, const int* in_sizes, int n_in,
                              void* d_out, int out_size, void* d_ws, size_t ws_size,
                              hipStream_t stream) {
    const float* x_mean = (const float*)d_in[0];
    const float* x_var  = (const float*)d_in[1];
    const float* z_param = (const float*)d_in[2];
    const float* h       = (const float*)d_in[3];
    const float* l_param = (const float*)d_in[4];
    const float* s_param = (const float*)d_in[5];
    const float* jitter_param = (const float*)d_in[6];
    float* out = (float*)d_out;

    if (ws_size >= NEED_BYTES) {
        gp_pairs<<<dim3(1024), dim3(64), 0, stream>>>(
            z_param, h, l_param, s_param, jitter_param, (float*)d_ws);
        gp_sites<<<dim3(NSB), dim3(256), 0, stream>>>(
            x_mean, x_var, (const float*)d_ws, (float*)d_ws);
        gp_reduce<<<dim3(256), dim3(128), 0, stream>>>(
            (const float*)d_ws, out);
    } else {
        hipMemsetAsync(d_out, 0, (size_t)out_size * sizeof(float), stream);
        gp_fused<<<dim3(2048), dim3(256), 0, stream>>>(
            x_mean, x_var, z_param, h, l_param, s_param, jitter_param, out);
    }
}

// Round 23
// 147.331 us; speedup vs baseline: 1.1072x; 1.1072x over previous
//
#include <hip/hip_runtime.h>
#include <math.h>

#define N_ 128
#define I_ 256
#define O_ 256
#define P_ 16
#define OT 4      // o's per block (site kernel)
#define IT 8      // i's per block (fallback kernel)
#define ITB 16    // i's per block (site kernel; optimum in BOTH regimes)
#define NSB 1024  // site blocks
#define ICH 4     // fallback kernel chunking
#define SQRT_2PI 2.5066282746310002f
#define INV_SQRT_2PI 0.3989422804014327f
#define NHALF_LOG2E 0.72134752044448170f   // 0.5 * log2(e)

// ---- Workspace layout ----
// floats [0, 4096*GF)           : packed records v3 (M f16, w/z/sc f32)
// floats [PM_OFF ...)           : pmean[block][ol][n]  (1024*4*128)
// floats [PV_OFF ...)           : pvar  same layout
// FINAL LADDER (all measured, 218.9 -> 148.6):
//  f16-M record -10; ITB 8->16 -27 (atomic halving); f16 passB -16;
//  su2-f16 -4; exp2-fold ~0; partial-stores+reduce -23 (atomics deleted,
//  WRITE 32768->4096). R22 retested ITB=8 in no-atomics regime: FETCH
//  17.4->27.5MB, WRITE->57MB (L2 thrash/writebacks), total +15 — ITB=16
//  is the memory-system optimum, occupancy is a non-lever in both regimes.
#define GF 2048                    // floats per 16-pair group
#define PM_OFF ((size_t)4096 * GF)             // 8,388,608 floats
#define PV_OFF (PM_OFF + (size_t)NSB * 4 * 128)
#define NEED_BYTES ((PV_OFF + (size_t)NSB * 4 * 128) * 4)   // 37.7 MB

#define TRI(r, c) ((r) * ((r) + 1) / 2 + (c))

typedef float f2 __attribute__((ext_vector_type(2)));
typedef _Float16 h2 __attribute__((ext_vector_type(2)));

__device__ __forceinline__ float fast_tanh(float x) {
    const float e2 = __expf(2.0f * x);
    return 1.0f - 2.0f / (e2 + 1.0f);
}

// f32x2 -> packed f16x2 (round-nearest via scalar casts)
__device__ __forceinline__ uint32_t pkh(float a, float b) {
    h2 h;
    h.x = (_Float16)a;
    h.y = (_Float16)b;
    return __builtin_bit_cast(uint32_t, h);
}

// ============================ Kernel 1: pairs ==============================
// Serial per-thread Cholesky + in-place inversion + w (measured best of 6
// structural variants); store packs M to f16 RN.
__global__ __launch_bounds__(64, 1) void gp_pairs(
    const float* __restrict__ z_param, const float* __restrict__ h,
    const float* __restrict__ l_param, const float* __restrict__ s_param,
    const float* __restrict__ jitter_param, float* __restrict__ ws)
{
    const int q = blockIdx.x * 64 + threadIdx.x;   // pair index = i*256 + o
    const int io = q;

    const float l   = __expf(l_param[io]) + 0.2f;
    const float s   = __expf(s_param[io]) + 0.1f;
    const float jit = __expf(jitter_param[io]) + 0.01f;
    const float l2 = l * l;
    const float ninv2l2 = -0.5f / l2;
    const float cQ = INV_SQRT_2PI / l;
    const float noise = jit * jit / (s * s * l * SQRT_2PI);
    const float s2l = s * s * l;

    float zv[P_], hv[P_];
    {
        const float4* zp = (const float4*)(z_param + (size_t)io * P_);
        const float4* hp = (const float4*)(h + (size_t)io * P_);
        #pragma unroll
        for (int c = 0; c < 4; ++c) {
            const float4 z4 = zp[c], h4 = hp[c];
            zv[4*c+0] = z4.x; zv[4*c+1] = z4.y; zv[4*c+2] = z4.z; zv[4*c+3] = z4.w;
            hv[4*c+0] = h4.x; hv[4*c+1] = h4.y; hv[4*c+2] = h4.z; hv[4*c+3] = h4.w;
        }
    }
    #pragma unroll
    for (int p = 0; p < P_; ++p) zv[p] = fast_tanh(zv[p]);

    float A[136];
    #pragma unroll
    for (int r = 0; r < P_; ++r) {
        #pragma unroll
        for (int c = 0; c <= r; ++c) {
            const float d = zv[r] - zv[c];
            A[TRI(r, c)] = cQ * __expf(d * d * ninv2l2) + ((r == c) ? noise : 0.f);
        }
    }

    float dinv[P_];
    #pragma unroll
    for (int k = 0; k < P_; ++k) {
        const float Lkk = sqrtf(A[TRI(k, k)]);
        const float ik = 1.0f / Lkk;
        dinv[k] = ik;
        A[TRI(k, k)] = Lkk;
        #pragma unroll
        for (int r = k + 1; r < P_; ++r) A[TRI(r, k)] *= ik;
        #pragma unroll
        for (int c = k + 1; c < P_; ++c) {
            const float Lck = A[TRI(c, k)];
            #pragma unroll
            for (int r = c; r < P_; ++r) A[TRI(r, c)] -= A[TRI(r, k)] * Lck;
        }
    }

    #pragma unroll
    for (int j = 0; j < P_; ++j) {
        #pragma unroll
        for (int r = j + 1; r < P_; ++r) {
            float acc = A[TRI(r, j)] * dinv[j];
            #pragma unroll
            for (int k = j + 1; k < r; ++k) acc += A[TRI(r, k)] * A[TRI(k, j)];
            A[TRI(r, j)] = -dinv[r] * acc;
        }
        A[TRI(j, j)] = dinv[j];
    }

    float tv[P_], wv[P_];
    #pragma unroll
    for (int r = 0; r < P_; ++r) {
        float acc = 0.f;
        #pragma unroll
        for (int c = 0; c <= r; ++c) acc += A[TRI(r, c)] * hv[c];
        tv[r] = acc;
    }
    #pragma unroll
    for (int c = 0; c < P_; ++c) {
        float acc = 0.f;
        #pragma unroll
        for (int r = c; r < P_; ++r) acc += A[TRI(r, c)] * tv[r];
        wv[c] = acc;
    }

    // ---- store packed record v3 ----
    float4* rb = (float4*)ws + (size_t)(q >> 4) * (GF / 4) + (size_t)(q & 15) * 4;
    {
        float4 buf[4];
        uint32_t us[4];
        int ucnt = 0, f4 = 0;
        #pragma unroll
        for (int m = 0; m < P_; ++m) {
            #pragma unroll
            for (int c = (m >> 2); c < 4; ++c) {
                float vv[4];
                #pragma unroll
                for (int rr = 0; rr < 4; ++rr) {
                    const int r = 4 * c + rr;
                    vv[rr] = (r < m) ? 0.f : A[TRI(r, m)];
                }
                us[ucnt]     = pkh(vv[0], vv[1]);
                us[ucnt + 1] = pkh(vv[2], vv[3]);
                ucnt += 2;
                if (ucnt == 4) {
                    buf[f4 & 3] = make_float4(
                        __uint_as_float(us[0]), __uint_as_float(us[1]),
                        __uint_as_float(us[2]), __uint_as_float(us[3]));
                    ucnt = 0;
                    if ((f4 & 3) == 3) {
                        float4* up = rb + (size_t)(f4 >> 2) * 64;
                        up[0] = buf[0]; up[1] = buf[1]; up[2] = buf[2]; up[3] = buf[3];
                    }
                    ++f4;
                }
            }
        }
    }
    {
        float4* zp = rb + 5 * 64;
        zp[0] = make_float4(zv[ 0], zv[ 1], zv[ 2], zv[ 3]);
        zp[1] = make_float4(zv[ 4], zv[ 5], zv[ 6], zv[ 7]);
        zp[2] = make_float4(zv[ 8], zv[ 9], zv[10], zv[11]);
        zp[3] = make_float4(zv[12], zv[13], zv[14], zv[15]);
        float4* wp = rb + 6 * 64;
        wp[0] = make_float4(wv[ 0], wv[ 1], wv[ 2], wv[ 3]);
        wp[1] = make_float4(wv[ 4], wv[ 5], wv[ 6], wv[ 7]);
        wp[2] = make_float4(wv[ 8], wv[ 9], wv[10], wv[11]);
        wp[3] = make_float4(wv[12], wv[13], wv[14], wv[15]);
        float4* sp = rb + 7 * 64;
        sp[0] = make_float4(l2, s2l, 0.f, 0.f);
    }
}

// ============================ Kernel 2: sites ==============================
// R21-exact (banked best, 148.6 total): ITB=16, grid 1024, atomic-free
// partial stores; f16 pass B + su2; exp2-folded pass A.
__global__ __launch_bounds__(256, 4) void gp_sites(
    const float* __restrict__ x_mean, const float* __restrict__ x_var,
    const float* __restrict__ ws, float* __restrict__ wsw)
{
    __shared__ float xm_s[N_][ITB + 1];
    __shared__ float xv_s[N_][ITB + 1];
    __shared__ __align__(16) float4 pbv[64 * 32];   // 64 records x 512B

    const int t = threadIdx.x;
    const int b = blockIdx.x;
    const int ot = b & 63;
    const int ir = b >> 6;          // 0..15
    const int i0 = ir * ITB;

    // stage x slice (16 i's x 128 n): each thread 2+2 float4s
    {
        const int n = t >> 1, qq = t & 1;
        const float4 xma = *(const float4*)(x_mean + n * I_ + i0 + qq * 8);
        const float4 xmb = *(const float4*)(x_mean + n * I_ + i0 + qq * 8 + 4);
        const float4 xva = *(const float4*)(x_var  + n * I_ + i0 + qq * 8);
        const float4 xvb = *(const float4*)(x_var  + n * I_ + i0 + qq * 8 + 4);
        xm_s[n][qq*8+0] = xma.x; xm_s[n][qq*8+1] = xma.y;
        xm_s[n][qq*8+2] = xma.z; xm_s[n][qq*8+3] = xma.w;
        xm_s[n][qq*8+4] = xmb.x; xm_s[n][qq*8+5] = xmb.y;
        xm_s[n][qq*8+6] = xmb.z; xm_s[n][qq*8+7] = xmb.w;
        xv_s[n][qq*8+0] = xva.x; xv_s[n][qq*8+1] = xva.y;
        xv_s[n][qq*8+2] = xva.z; xv_s[n][qq*8+3] = xva.w;
        xv_s[n][qq*8+4] = xvb.x; xv_s[n][qq*8+5] = xvb.y;
        xv_s[n][qq*8+6] = xvb.z; xv_s[n][qq*8+7] = xvb.w;
    }

    // stage all 64 records (16 i x 4 o), coalesced: exactly 2048 float4s
    {
        const int g_hi = ot >> 2;
        const int s0x4 = (ot & 3) * 16;         // s0*4 in float4 units
        const float4* wsv = (const float4*)ws;
        #pragma unroll
        for (int k = 0; k < 8; ++k) {
            const int idx = t + k * 256;
            const int run = idx >> 4;           // 0..127 = i*8 + j
            const int f4i = idx & 15;           // ol*4 + c
            const int i = run >> 3;             // 0..15
            const int j = run & 7;
            const int gi = (i0 + i) * 16 + g_hi;
            const float4 v = wsv[(size_t)gi * (GF / 4) + j * 64 + s0x4 + f4i];
            pbv[(i * 4 + (f4i >> 2)) * 32 + j * 4 + (f4i & 3)] = v;
        }
    }
    __syncthreads();

    f2 am2 = {0.f, 0.f};
    f2 av2 = {ITB * 0.1f, ITB * 0.1f};   // GLOBAL_JITTER per i

    const int ol = t >> 6;   // o_local (0..3), one per wave
    const int ln = t & 63;   // sites n = ln and ln+64

    // chunk lk -> (column m, row-quad c), producer's order (R5-verified)
    constexpr int MKt[40] = {0,0,0,0, 1,1,1,1, 2,2,2,2, 3,3,3,3,
                             4,4,4, 5,5,5, 6,6,6, 7,7,7,
                             8,8, 9,9, 10,10, 11,11, 12, 13, 14, 15};
    constexpr int CKt[40] = {0,1,2,3, 0,1,2,3, 0,1,2,3, 0,1,2,3,
                             1,2,3, 1,2,3, 1,2,3, 1,2,3,
                             2,3, 2,3, 2,3, 2,3, 3, 3, 3, 3};

    for (int ii = 0; ii < ITB; ++ii) {
        const float4* rp = &pbv[(ii * 4 + ol) * 32];

        const float4 scv = rp[28];
        const float l2  = scv.x;
        const float s2l = scv.y;
        const float t4v = SQRT_2PI * s2l;

        float zr[P_], wr[P_];
        #pragma unroll
        for (int c = 0; c < 4; ++c) {
            const float4 z4 = rp[20 + c], w4 = rp[24 + c];
            zr[4*c+0] = z4.x; zr[4*c+1] = z4.y; zr[4*c+2] = z4.z; zr[4*c+3] = z4.w;
            wr[4*c+0] = w4.x; wr[4*c+1] = w4.y; wr[4*c+2] = w4.z; wr[4*c+3] = w4.w;
        }

        f2 xm2, xv2;
        xm2.x = xm_s[ln][ii];       xm2.y = xm_s[ln + 64][ii];
        xv2.x = xv_s[ln][ii];       xv2.y = xv_s[ln + 64][ii];
        f2 v2 = xv2 + l2;
        f2 cc2, nh2;
        cc2.x = rsqrtf(v2.x) * INV_SQRT_2PI;
        cc2.y = rsqrtf(v2.y) * INV_SQRT_2PI;
        nh2.x = -NHALF_LOG2E / v2.x;   // -0.5*log2e/v: em = exp2(d^2*nh2)
        nh2.y = -NHALF_LOG2E / v2.y;

        // ---- pass A: all 16 em2 (f32), dm2 (f32, parity-split) ----
        f2 em2[P_];
        h2 em2h[P_];
        f2 dm2a = {0.f, 0.f}, dm2b = {0.f, 0.f};
        #pragma unroll
        for (int m = 0; m < P_; ++m) {
            f2 d2 = xm2 - zr[m];
            f2 tt = d2 * d2 * nh2;
            em2[m].x = __builtin_amdgcn_exp2f(tt.x);
            em2[m].y = __builtin_amdgcn_exp2f(tt.y);
            em2h[m].x = (_Float16)em2[m].x;
            em2h[m].y = (_Float16)em2[m].y;
            if (m & 1) dm2b += em2[m] * wr[m];
            else       dm2a += em2[m] * wr[m];
        }
        const f2 dm2 = dm2a + dm2b;

        // ---- pass B: 20 float4 reads = 40 f16 chunks, native f16 pk-fma ----
        h2 u2h[P_];
        #pragma unroll
        for (int tt = 0; tt < 20; ++tt) {
            const float4 F = rp[tt];
            const h2 pa = __builtin_bit_cast(h2, F.x);
            const h2 pb = __builtin_bit_cast(h2, F.y);
            const h2 pc = __builtin_bit_cast(h2, F.z);
            const h2 pd = __builtin_bit_cast(h2, F.w);
            {   // chunk 2*tt : values pa.x pa.y pb.x pb.y
                const int lk = 2 * tt;
                const int m = MKt[lk], c = CKt[lk];
                if (lk < 4) {
                    u2h[4*c+0] = pa.x * em2h[m];
                    u2h[4*c+1] = pa.y * em2h[m];
                    u2h[4*c+2] = pb.x * em2h[m];
                    u2h[4*c+3] = pb.y * em2h[m];
                } else {
                    u2h[4*c+0] += pa.x * em2h[m];
                    u2h[4*c+1] += pa.y * em2h[m];
                    u2h[4*c+2] += pb.x * em2h[m];
                    u2h[4*c+3] += pb.y * em2h[m];
                }
            }
            {   // chunk 2*tt+1 : values pc.x pc.y pd.x pd.y
                const int lk = 2 * tt + 1;
                const int m = MKt[lk], c = CKt[lk];
                if (lk < 4) {
                    u2h[4*c+0] = pc.x * em2h[m];
                    u2h[4*c+1] = pc.y * em2h[m];
                    u2h[4*c+2] = pd.x * em2h[m];
                    u2h[4*c+3] = pd.y * em2h[m];
                } else {
                    u2h[4*c+0] += pc.x * em2h[m];
                    u2h[4*c+1] += pc.y * em2h[m];
                    u2h[4*c+2] += pd.x * em2h[m];
                    u2h[4*c+3] += pd.y * em2h[m];
                }
            }
        }

        // ---- su2 accumulated packed-f16 (parity-split), one up-convert ----
        h2 su2ha = {(_Float16)0.f, (_Float16)0.f};
        h2 su2hb = {(_Float16)0.f, (_Float16)0.f};
        #pragma unroll
        for (int r = 0; r < P_; r += 2) {
            su2ha += u2h[r]   * u2h[r];
            su2hb += u2h[r+1] * u2h[r+1];
        }
        const h2 su2h = su2ha + su2hb;
        f2 su2;
        su2.x = (float)su2h.x;
        su2.y = (float)su2h.y;

        am2 += cc2 * dm2;
        f2 t32;
        t32.x = s2l * rsqrtf(l2 + 2.f * xv2.x);
        t32.y = s2l * rsqrtf(l2 + 2.f * xv2.y);
        av2 += t32 - t4v * (cc2 * cc2) * su2;
    }

    // ---- coalesced partial stores (no atomics) ----
    float* pm = wsw + PM_OFF + ((size_t)b * 4 + ol) * 128;
    float* pv = wsw + PV_OFF + ((size_t)b * 4 + ol) * 128;
    pm[ln]      = am2.x;
    pm[ln + 64] = am2.y;
    pv[ln]      = av2.x;
    pv[ln + 64] = av2.y;
}

// ============================ Kernel 3: reduce =============================
// out[n][o] = sum_ir pmean[(ir*64+ot)*4+ol][n]; same for var. One block per
// o (256 blocks x 128 threads = n); partial loads coalesced (lanes = n).
__global__ __launch_bounds__(128, 8) void gp_reduce(
    const float* __restrict__ ws, float* __restrict__ out)
{
    const int o = blockIdx.x;
    const int n = threadIdx.x;
    const int ot = o >> 2;
    const int ol = o & 3;

    const float* pm = ws + PM_OFF;
    const float* pv = ws + PV_OFF;

    float sm = 0.f, sv = 0.f;
    #pragma unroll
    for (int ir = 0; ir < 16; ++ir) {
        const size_t base = (((size_t)ir * 64 + ot) * 4 + ol) * 128 + n;
        sm += pm[base];
        sv += pv[base];
    }
    out[n * O_ + o] = sm;
    out[N_ * O_ + n * O_ + o] = sv;
}

// ===================== Fallback: R5 monolithic kernel ======================
#define LSTR 20
__global__ __launch_bounds__(256, 2) void gp_fused(
    const float* __restrict__ x_mean, const float* __restrict__ x_var,
    const float* __restrict__ z_param, const float* __restrict__ h,
    const float* __restrict__ l_param, const float* __restrict__ s_param,
    const float* __restrict__ jitter_param, float* __restrict__ out)
{
    __shared__ float xm_s[N_][IT + 1];
    __shared__ float xv_s[N_][IT + 1];
    __shared__ __align__(16) float LinvT[ICH][OT][P_][LSTR];
    __shared__ __align__(16) float zS[ICH][OT][P_];
    __shared__ __align__(16) float wS[ICH][OT][P_];
    __shared__ float scS[ICH][OT][2];

    const int t = threadIdx.x;
    const int b = blockIdx.x;
    const int ot = b & 63;
    const int ir = b >> 6;
    const int o_base = ot * OT;
    const int i0 = ir * IT;

    {
        const int n = t >> 1, q = t & 1;
        const float4 xm4 = *(const float4*)(x_mean + n * I_ + i0 + q * 4);
        const float4 xv4 = *(const float4*)(x_var  + n * I_ + i0 + q * 4);
        xm_s[n][q*4+0] = xm4.x; xm_s[n][q*4+1] = xm4.y;
        xm_s[n][q*4+2] = xm4.z; xm_s[n][q*4+3] = xm4.w;
        xv_s[n][q*4+0] = xv4.x; xv_s[n][q*4+1] = xv4.y;
        xv_s[n][q*4+2] = xv4.z; xv_s[n][q*4+3] = xv4.w;
    }
    __syncthreads();

    f2 am2 = {0.f, 0.f};
    f2 av2 = {IT * 0.1f, IT * 0.1f};

    const int ol = t >> 6;
    const int ln = t & 63;
    const int g2 = t >> 4;
    const int il = g2 >> 2;
    const int g  = g2 & 3;
    const int p  = t & 15;

    for (int ii4 = 0; ii4 < IT / ICH; ++ii4) {
        {
            const int i  = i0 + ii4 * ICH + il;
            const int o  = o_base + g;
            const int io = i * O_ + o;
            const float l   = expf(l_param[io]) + 0.2f;
            const float s   = expf(s_param[io]) + 0.1f;
            const float jit = expf(jitter_param[io]) + 0.01f;
            const float l2 = l * l;
            const float inv2l2 = 0.5f / l2;
            const float cQ = INV_SQRT_2PI / l;
            const float noise = jit * jit / (s * s * l * SQRT_2PI);
            const float zp = tanhf(z_param[io * P_ + p]);

            float a[P_];
            #pragma unroll
            for (int c = 0; c < P_; ++c) {
                const float zc = __shfl(zp, c, P_);
                const float d = zp - zc;
                a[c] = cQ * __expf(-d * d * inv2l2) + ((c == p) ? noise : 0.0f);
            }
            #pragma unroll
            for (int k = 0; k < P_; ++k) {
                const float akk = __shfl(a[k], k, P_);
                const float lkk = sqrtf(akk);
                const float inv_lkk = 1.0f / lkk;
                if (p == k)      a[k] = lkk;
                else if (p > k)  a[k] *= inv_lkk;
                const float lrk = a[k];
                #pragma unroll
                for (int c = k + 1; c < P_; ++c) {
                    const float lck = __shfl(a[k], c, P_);
                    if (p >= c) a[c] -= lrk * lck;
                }
            }
            float x[P_];
            #pragma unroll
            for (int r = 0; r < P_; ++r) {
                const float lrr = __shfl(a[r], r, P_);
                float acc = (r == p) ? 1.0f : 0.0f;
                #pragma unroll
                for (int m = 0; m < r; ++m) {
                    const float lrm = __shfl(a[m], r, P_);
                    acc -= lrm * x[m];
                }
                x[r] = acc / lrr;
            }
            const float hc = h[io * P_ + p];
            float y[P_];
            #pragma unroll
            for (int r = 0; r < P_; ++r) y[r] = x[r] * hc;
            #pragma unroll
            for (int off = 8; off >= 1; off >>= 1) {
                #pragma unroll
                for (int r = 0; r < P_; ++r) y[r] += __shfl_xor(y[r], off, P_);
            }
            float wc = 0.f;
            #pragma unroll
            for (int r = 0; r < P_; ++r) wc += x[r] * y[r];

            float4* dst = (float4*)&LinvT[il][g][p][0];
            dst[0] = make_float4(x[ 0], x[ 1], x[ 2], x[ 3]);
            dst[1] = make_float4(x[ 4], x[ 5], x[ 6], x[ 7]);
            dst[2] = make_float4(x[ 8], x[ 9], x[10], x[11]);
            dst[3] = make_float4(x[12], x[13], x[14], x[15]);
            zS[il][g][p] = zp;
            wS[il][g][p] = wc;
            if (p == 0) { scS[il][g][0] = l2; scS[il][g][1] = s * s * l; }
        }
        __syncthreads();

        #pragma unroll
        for (int il2 = 0; il2 < ICH; ++il2) {
            const int iiA = ii4 * ICH + il2;
            const float l2  = scS[il2][ol][0];
            const float s2l = scS[il2][ol][1];
            const float t4v = SQRT_2PI * s2l;
            float zr[P_], wr[P_];
            {
                const float4* zp4 = (const float4*)&zS[il2][ol][0];
                const float4* wp4 = (const float4*)&wS[il2][ol][0];
                #pragma unroll
                for (int c = 0; c < 4; ++c) {
                    const float4 z4 = zp4[c], w4 = wp4[c];
                    zr[4*c+0] = z4.x; zr[4*c+1] = z4.y; zr[4*c+2] = z4.z; zr[4*c+3] = z4.w;
                    wr[4*c+0] = w4.x; wr[4*c+1] = w4.y; wr[4*c+2] = w4.z; wr[4*c+3] = w4.w;
                }
            }
            f2 xm2, xv2;
            xm2.x = xm_s[ln][iiA];       xm2.y = xm_s[ln + 64][iiA];
            xv2.x = xv_s[ln][iiA];       xv2.y = xv_s[ln + 64][iiA];
            f2 v2 = xv2 + l2;
            f2 cc2, nh2;
            cc2.x = rsqrtf(v2.x) * INV_SQRT_2PI;
            cc2.y = rsqrtf(v2.y) * INV_SQRT_2PI;
            nh2.x = -0.5f / v2.x;
            nh2.y = -0.5f / v2.y;
            f2 dm2 = {0.f, 0.f};
            f2 u2[P_];
            #pragma unroll
            for (int m = 0; m < P_; ++m) {
                f2 d2 = xm2 - zr[m];
                f2 tt = d2 * d2 * nh2;
                f2 em2;
                em2.x = __expf(tt.x);
                em2.y = __expf(tt.y);
                dm2 += em2 * wr[m];
                const int c0 = m >> 2;
                #pragma unroll
                for (int c = 0; c < 4; ++c) {
                    if (c < c0) continue;
                    const float4 L4 = *(const float4*)&LinvT[il2][ol][m][4*c];
                    if (m == 0) {
                        u2[4*c+0] = L4.x * em2;
                        u2[4*c+1] = L4.y * em2;
                        u2[4*c+2] = L4.z * em2;
                        u2[4*c+3] = L4.w * em2;
                    } else {
                        u2[4*c+0] += L4.x * em2;
                        u2[4*c+1] += L4.y * em2;
                        u2[4*c+2] += L4.z * em2;
                        u2[4*c+3] += L4.w * em2;
                    }
                }
            }
            f2 su2 = {0.f, 0.f};
            #pragma unroll
            for (int r = 0; r < P_; ++r) su2 += u2[r] * u2[r];
            am2 += cc2 * dm2;
            f2 t32;
            t32.x = s2l * rsqrtf(l2 + 2.f * xv2.x);
            t32.y = s2l * rsqrtf(l2 + 2.f * xv2.y);
            av2 += t32 - t4v * (cc2 * cc2) * su2;
        }
        __syncthreads();
    }

    const int o = o_base + ol;
    atomicAdd(out + ln * O_ + o,                  am2.x);
    atomicAdd(out + (ln + 64) * O_ + o,           am2.y);
    atomicAdd(out + N_ * O_ + ln * O_ + o,        av2.x);
    atomicAdd(out + N_ * O_ + (ln + 64) * O_ + o, av2.y);
}

extern "C" void kernel_launch(void* const* d_in, const int* in_sizes, int n_in,
                              void* d_out, int out_size, void* d_ws, size_t ws_size,
                              hipStream_t stream) {
    const float* x_mean = (const float*)d_in[0];
    const float* x_var  = (const float*)d_in[1];
    const float* z_param = (const float*)d_in[2];
    const float* h       = (const float*)d_in[3];
    const float* l_param = (const float*)d_in[4];
    const float* s_param = (const float*)d_in[5];
    const float* jitter_param = (const float*)d_in[6];
    float* out = (float*)d_out;

    if (ws_size >= NEED_BYTES) {
        gp_pairs<<<dim3(1024), dim3(64), 0, stream>>>(
            z_param, h, l_param, s_param, jitter_param, (float*)d_ws);
        gp_sites<<<dim3(NSB), dim3(256), 0, stream>>>(
            x_mean, x_var, (const float*)d_ws, (float*)d_ws);
        gp_reduce<<<dim3(256), dim3(128), 0, stream>>>(
            (const float*)d_ws, out);
    } else {
        hipMemsetAsync(d_out, 0, (size_t)out_size * sizeof(float), stream);
        gp_fused<<<dim3(2048), dim3(256), 0, stream>>>(
            x_mean, x_var, z_param, h, l_param, s_param, jitter_param, out);
    }
}